// Round 11
// baseline (89.164 us; speedup 1.0000x reference)
//
#include <hip/hip_runtime.h>

#define HIDDEN 128

typedef _Float16 f16x8 __attribute__((ext_vector_type(8)));
typedef _Float16 f16x4 __attribute__((ext_vector_type(4)));
typedef _Float16 f16x2 __attribute__((ext_vector_type(2)));
typedef __fp16   fp16v2 __attribute__((ext_vector_type(2)));  // builtin ABI type
typedef float f32x4 __attribute__((ext_vector_type(4)));

// ---------------------------------------------------------------------------
// Kernel 0: pack W1 (fp32, (256,128)) into fp16 MFMA fragments.
// Bmat (K=128, N=256): Bmat[k][n] = n<128 ? W1[k][n] : W1[128+k][n-128]
// Wpk[((jt*4+kt)*64 + lane)*8 + j] = Bmat[kt*32+(lane>>4)*8+j][jt*16+(lane&15)]
// Serves as A-operand fragment (A = Bmat^T): lane holds A[lane&15][(lane>>4)*8+j].
// ---------------------------------------------------------------------------
__global__ __launch_bounds__(64) void prep_w(const float* __restrict__ W1,
                                             _Float16* __restrict__ Wpk) {
  const int blk = blockIdx.x;        // 0..63 = jt*4 + kt
  const int jt = blk >> 2;
  const int kt = blk & 3;
  const int lane = threadIdx.x;      // 0..63
  const int col = jt * 16 + (lane & 15);         // feature 0..255
  const int kbase = kt * 32 + (lane >> 4) * 8;   // 0..120
  f16x8 v;
#pragma unroll
  for (int j = 0; j < 8; ++j) {
    const int k = kbase + j;
    const float w = (col < HIDDEN) ? W1[k * HIDDEN + col]
                                   : W1[(HIDDEN + k) * HIDDEN + (col - HIDDEN)];
    v[j] = (_Float16)w;
  }
  *reinterpret_cast<f16x8*>(Wpk + ((size_t)blk * 64 + lane) * 8) = v;
}

// ---------------------------------------------------------------------------
// Kernel 1 (v9, unchanged): 4 tiles/block, static depth-2 pipeline, stores
// only at the end after one barrier. ~38us inferred; revisit once it's back
// in the profiled top-5.
// ---------------------------------------------------------------------------
__global__ __launch_bounds__(256) void gemm_mfma_v9(
    const float* __restrict__ h, const _Float16* __restrict__ Wpk,
    const float* __restrict__ b1, _Float16* __restrict__ Af,
    _Float16* __restrict__ Bf, int n_nodes, int ntiles) {
  __shared__ __align__(16) char out_lds[4 * 16 * 528];

  const int tid = threadIdx.x;
  const int lane = tid & 63;
  const int wave = tid >> 6;
  const int nl = lane & 15;
  const int kgrp = lane >> 4;
  const int jt0 = wave * 4;
  const int t0 = blockIdx.x * 4;
  if (t0 >= ntiles) return;

  const f16x8* wp = reinterpret_cast<const f16x8*>(Wpk);
  f16x8 wfrag[4][4];
#pragma unroll
  for (int j4 = 0; j4 < 4; ++j4)
#pragma unroll
    for (int kt = 0; kt < 4; ++kt)
      wfrag[j4][kt] = wp[((jt0 + j4) * 4 + kt) * 64 + lane];

  f32x4 binit[4];
#pragma unroll
  for (int j4 = 0; j4 < 4; ++j4) {
    const int jt = jt0 + j4;
    if (jt < 8) {
      binit[j4] = *reinterpret_cast<const f32x4*>(b1 + jt * 16 + kgrp * 4);
    } else {
      binit[j4][0] = 0.f; binit[j4][1] = 0.f; binit[j4][2] = 0.f; binit[j4][3] = 0.f;
    }
  }

  float4 buf0[8], buf1[8];
  f16x8 hfrag[4];

  auto LOAD = [&](float4* buf, int tile) {
    int node = tile * 16 + nl;
    if (node >= n_nodes) node = 0;
    const float4* hp = reinterpret_cast<const float4*>(h) +
                       (size_t)node * 32 + kgrp * 2;
#pragma unroll
    for (int kt = 0; kt < 4; ++kt) {
      buf[kt * 2]     = hp[kt * 8];
      buf[kt * 2 + 1] = hp[kt * 8 + 1];
    }
  };

  auto CVT = [&](const float4* buf) {
#pragma unroll
    for (int kt = 0; kt < 4; ++kt) {
      const float4 v0 = buf[kt * 2];
      const float4 v1 = buf[kt * 2 + 1];
      const fp16v2 p0 = __builtin_amdgcn_cvt_pkrtz(v0.x, v0.y);
      const fp16v2 p1 = __builtin_amdgcn_cvt_pkrtz(v0.z, v0.w);
      const fp16v2 p2 = __builtin_amdgcn_cvt_pkrtz(v1.x, v1.y);
      const fp16v2 p3 = __builtin_amdgcn_cvt_pkrtz(v1.z, v1.w);
      hfrag[kt][0] = (_Float16)p0[0]; hfrag[kt][1] = (_Float16)p0[1];
      hfrag[kt][2] = (_Float16)p1[0]; hfrag[kt][3] = (_Float16)p1[1];
      hfrag[kt][4] = (_Float16)p2[0]; hfrag[kt][5] = (_Float16)p2[1];
      hfrag[kt][6] = (_Float16)p3[0]; hfrag[kt][7] = (_Float16)p3[1];
    }
  };

  auto COMPUTE_DSWRITE = [&](int i) {
    f32x4 acc[4];
#pragma unroll
    for (int j4 = 0; j4 < 4; ++j4) acc[j4] = binit[j4];
#pragma unroll
    for (int kt = 0; kt < 4; ++kt)
#pragma unroll
      for (int j4 = 0; j4 < 4; ++j4)
        acc[j4] = __builtin_amdgcn_mfma_f32_16x16x32_f16(
            wfrag[j4][kt], hfrag[kt], acc[j4], 0, 0, 0);
#pragma unroll
    for (int j4 = 0; j4 < 4; ++j4) {
      const int jt = jt0 + j4;
      const int byte = i * 8448 + nl * 528 +
                       ((jt & 7) * 16 + kgrp * 4) * 2 + ((jt >= 8) ? 256 : 0);
      f16x4 v;
      v[0] = (_Float16)acc[j4][0];
      v[1] = (_Float16)acc[j4][1];
      v[2] = (_Float16)acc[j4][2];
      v[3] = (_Float16)acc[j4][3];
      *reinterpret_cast<f16x4*>(out_lds + byte) = v;
    }
  };

  LOAD(buf0, t0);
  LOAD(buf1, t0 + 1);
  CVT(buf0); LOAD(buf0, t0 + 2); COMPUTE_DSWRITE(0);
  CVT(buf1); LOAD(buf1, t0 + 3); COMPUTE_DSWRITE(1);
  CVT(buf0);                     COMPUTE_DSWRITE(2);
  CVT(buf1);                     COMPUTE_DSWRITE(3);

  __syncthreads();

  const int cn = tid >> 4;
  const int seg = tid & 15;
#pragma unroll
  for (int i = 0; i < 4; ++i) {
    const int node = (t0 + i) * 16 + cn;
    if (node < n_nodes) {
      const f16x8 a = *reinterpret_cast<const f16x8*>(
          out_lds + i * 8448 + cn * 528 + seg * 16);
      const f16x8 b = *reinterpret_cast<const f16x8*>(
          out_lds + i * 8448 + cn * 528 + 256 + seg * 16);
      *reinterpret_cast<f16x8*>(Af + (size_t)node * HIDDEN + seg * 8) = a;
      *reinterpret_cast<f16x8*>(Bf + (size_t)node * HIDDEN + seg * 8) = b;
    }
  }
}

// ---------------------------------------------------------------------------
// Kernel 2 (v5): edge scoring with FORCED memory-level parallelism.
// v4 post-mortem: VGPR_Count=28 < the 32 regs needed just for av[]+bv[] ->
// compiler sank the gathers into the consume loop (~8 in flight). Here all
// 32 gathers are issued first, then sched_barrier(0) fences the scheduler so
// consumes can't migrate up / loads can't sink down. Consume order matches
// issue order -> progressive counted vmcnt drain.
// ---------------------------------------------------------------------------
__global__ __launch_bounds__(256) void edge_score_v5(
    const int* __restrict__ ei, const _Float16* __restrict__ Af,
    const _Float16* __restrict__ Bf, const float* __restrict__ W2,
    const float* __restrict__ b2, float* __restrict__ out, int n_edges) {
  const int wid = (int)((blockIdx.x * 256 + threadIdx.x) >> 6);
  const int lane = threadIdx.x & 63;
  const int e0 = wid * 16;
  if (e0 >= n_edges) return;

  // Uniform index loads (vector int4 -> scalar dwordx4 when in range).
  int srcs[16], dsts[16];
  if (e0 + 16 <= n_edges) {
    const int4* sp = reinterpret_cast<const int4*>(ei + e0);
    const int4* dp = reinterpret_cast<const int4*>(ei + n_edges + e0);
#pragma unroll
    for (int q = 0; q < 4; ++q) {
      const int4 s4 = sp[q], d4 = dp[q];
      srcs[q * 4] = s4.x; srcs[q * 4 + 1] = s4.y; srcs[q * 4 + 2] = s4.z; srcs[q * 4 + 3] = s4.w;
      dsts[q * 4] = d4.x; dsts[q * 4 + 1] = d4.y; dsts[q * 4 + 2] = d4.z; dsts[q * 4 + 3] = d4.w;
    }
  } else {
#pragma unroll
    for (int k = 0; k < 16; ++k) {
      const int e = (e0 + k < n_edges) ? e0 + k : n_edges - 1;
      srcs[k] = ei[e];
      dsts[k] = ei[n_edges + e];
    }
  }

  const char* Afc = (const char*)Af;
  const char* Bfc = (const char*)Bf;
  const unsigned int loff = (unsigned int)(lane << 2);

  // Issue ALL 32 gathers (pairwise so consume k waits only on the 2k oldest).
  f16x2 av[16], bv[16];
#pragma unroll
  for (int k = 0; k < 16; ++k) {
    av[k] = *reinterpret_cast<const f16x2*>(Afc + (((unsigned int)srcs[k] << 8) + loff));
    bv[k] = *reinterpret_cast<const f16x2*>(Bfc + (((unsigned int)dsts[k] << 8) + loff));
  }
  __builtin_amdgcn_sched_barrier(0);  // keep all 32 loads in flight

  const float2 w2v = reinterpret_cast<const float2*>(W2)[lane];
  const fp16v2 w2h = __builtin_amdgcn_cvt_pkrtz(w2v.x, w2v.y);
  const _Float16 h0 = (_Float16)0.f;

  float p[16];
#pragma unroll
  for (int k = 0; k < 16; ++k) {
    f16x2 s = av[k] + bv[k];                 // v_pk_add_f16
    s[0] = s[0] > h0 ? s[0] : h0;            // pk max vs 0
    s[1] = s[1] > h0 ? s[1] : h0;
    p[k] = __builtin_amdgcn_fdot2(__builtin_bit_cast(fp16v2, s), w2h, 0.f, false);
  }

  auto mrg = [&](float a, float b, int off) {
    const float as = a + __shfl_xor(a, off, 64);
    const float bs = b + __shfl_xor(b, off, 64);
    return (lane & off) ? bs : as;
  };
  float q[8];
#pragma unroll
  for (int i = 0; i < 8; ++i) q[i] = mrg(p[2 * i], p[2 * i + 1], 1);
  float r[4];
#pragma unroll
  for (int i = 0; i < 4; ++i) r[i] = mrg(q[2 * i], q[2 * i + 1], 2);
  float s2[2];
#pragma unroll
  for (int i = 0; i < 2; ++i) s2[i] = mrg(r[2 * i], r[2 * i + 1], 4);
  float t = mrg(s2[0], s2[1], 8);
  t += __shfl_xor(t, 16, 64);
  t += __shfl_xor(t, 32, 64);

  if (lane < 16 && e0 + lane < n_edges) out[e0 + lane] = t + b2[0];
}

// ---------------------------------------------------------------------------
// Fallback (ws too small): fused fp32 per-edge compute.
// ---------------------------------------------------------------------------
__global__ __launch_bounds__(256) void fused_fallback(
    const float* __restrict__ h, const int* __restrict__ ei,
    const float* __restrict__ W1, const float* __restrict__ b1,
    const float* __restrict__ W2, const float* __restrict__ b2,
    float* __restrict__ out, int n_edges) {
  const int e = (int)((blockIdx.x * 256 + threadIdx.x) >> 6);
  const int lane = threadIdx.x & 63;
  if (e >= n_edges) return;
  const int src = ei[e], dst = ei[n_edges + e];
  const float* hs = h + (size_t)src * HIDDEN;
  const float* hd = h + (size_t)dst * HIDDEN;
  float acc0 = b1[lane], acc1 = b1[lane + 64];
  for (int k = 0; k < HIDDEN; ++k) {
    const float s = hs[k], d = hd[k];
    acc0 = fmaf(s, W1[k * HIDDEN + lane], acc0);
    acc0 = fmaf(d, W1[(k + HIDDEN) * HIDDEN + lane], acc0);
    acc1 = fmaf(s, W1[k * HIDDEN + lane + 64], acc1);
    acc1 = fmaf(d, W1[(k + HIDDEN) * HIDDEN + lane + 64], acc1);
  }
  acc0 = acc0 > 0.f ? acc0 : 0.f;
  acc1 = acc1 > 0.f ? acc1 : 0.f;
  float p = fmaf(acc0, W2[lane], acc1 * W2[lane + 64]);
#pragma unroll
  for (int off = 32; off >= 1; off >>= 1) p += __shfl_down(p, off, 64);
  if (lane == 0) out[e] = p + b2[0];
}

extern "C" void kernel_launch(void* const* d_in, const int* in_sizes, int n_in,
                              void* d_out, int out_size, void* d_ws, size_t ws_size,
                              hipStream_t stream) {
  const float* h  = (const float*)d_in[0];
  const int*   ei = (const int*)d_in[1];
  const float* W1 = (const float*)d_in[2];
  const float* b1 = (const float*)d_in[3];
  const float* W2 = (const float*)d_in[4];
  const float* b2 = (const float*)d_in[5];
  float* out = (float*)d_out;

  const int n_nodes = in_sizes[0] / HIDDEN;  // 100000
  const int n_edges = in_sizes[1] / 2;       // 640000

  const size_t wpk_halfs  = 64 * 64 * 8;                       // 32768
  const size_t proj_halfs = (size_t)n_nodes * HIDDEN;          // 12.8M
  const size_t need = (wpk_halfs + 2 * proj_halfs) * sizeof(_Float16);

  if (ws_size >= need) {
    _Float16* Wpk = (_Float16*)d_ws;
    _Float16* A   = Wpk + wpk_halfs;
    _Float16* B   = A + proj_halfs;

    prep_w<<<64, 64, 0, stream>>>(W1, Wpk);

    const int ntiles = (n_nodes + 15) / 16;       // 6250
    const int gblocks = (ntiles + 3) / 4;         // 1563
    gemm_mfma_v9<<<gblocks, 256, 0, stream>>>(h, Wpk, b1, A, B, n_nodes, ntiles);

    const int nwaves = (n_edges + 15) / 16;
    const int eblocks = (nwaves + 3) / 4;
    edge_score_v5<<<eblocks, 256, 0, stream>>>(ei, A, B, W2, b2, out, n_edges);
  } else {
    const int eblocks = (n_edges + 3) / 4;
    fused_fallback<<<eblocks, 256, 0, stream>>>(h, ei, W1, b1, W2, b2, out, n_edges);
  }
}

// Round 12
// 77.544 us; speedup vs baseline: 1.1498x; 1.1498x over previous
//
#include <hip/hip_runtime.h>

#define HIDDEN 128

typedef _Float16 f16x8 __attribute__((ext_vector_type(8)));
typedef _Float16 f16x4 __attribute__((ext_vector_type(4)));
typedef _Float16 f16x2 __attribute__((ext_vector_type(2)));
typedef __fp16   fp16v2 __attribute__((ext_vector_type(2)));  // builtin ABI type
typedef float f32x4 __attribute__((ext_vector_type(4)));

// ---------------------------------------------------------------------------
// Kernel 0: pack W1 (fp32, (256,128)) into fp16 MFMA fragments.
// Bmat (K=128, N=256): Bmat[k][n] = n<128 ? W1[k][n] : W1[128+k][n-128]
// Wpk[((jt*4+kt)*64 + lane)*8 + j] = Bmat[kt*32+(lane>>4)*8+j][jt*16+(lane&15)]
// Serves as A-operand fragment (A = Bmat^T): lane holds A[lane&15][(lane>>4)*8+j].
// ---------------------------------------------------------------------------
__global__ __launch_bounds__(64) void prep_w(const float* __restrict__ W1,
                                             _Float16* __restrict__ Wpk) {
  const int blk = blockIdx.x;        // 0..63 = jt*4 + kt
  const int jt = blk >> 2;
  const int kt = blk & 3;
  const int lane = threadIdx.x;      // 0..63
  const int col = jt * 16 + (lane & 15);         // feature 0..255
  const int kbase = kt * 32 + (lane >> 4) * 8;   // 0..120
  f16x8 v;
#pragma unroll
  for (int j = 0; j < 8; ++j) {
    const int k = kbase + j;
    const float w = (col < HIDDEN) ? W1[k * HIDDEN + col]
                                   : W1[(HIDDEN + k) * HIDDEN + (col - HIDDEN)];
    v[j] = (_Float16)w;
  }
  *reinterpret_cast<f16x8*>(Wpk + ((size_t)blk * 64 + lane) * 8) = v;
}

// ---------------------------------------------------------------------------
// Kernel 1 (v10): canonical LDS-staged GEMM. Root-cause theory for the
// ~40us plateau of v3-v9: direct fragment loads are address-scattered (each
// wave-instruction touches 32 half-used 64B lines) -> vector-memory REQUEST
// throughput bound, not bytes. Fix: dense staging loads (1KB contiguous per
// instruction), fp16-convert, XOR-swizzled LDS tile, ds_read_b128 fragments,
// LDS-bounce epilogue with dense stores (proven in v8). One 32-node macro-
// tile per block, 3125 blocks, no loop, 2 barriers total.
// ---------------------------------------------------------------------------
__global__ __launch_bounds__(256) void gemm_mfma_v10(
    const float* __restrict__ h, const _Float16* __restrict__ Wpk,
    const float* __restrict__ b1, _Float16* __restrict__ Af,
    _Float16* __restrict__ Bf, int n_nodes) {
  __shared__ __align__(16) char stage[32 * 256];   // fp16 h-tile, swizzled
  __shared__ __align__(16) char obuf[32 * 528];    // output bounce

  const int tid = threadIdx.x;
  const int lane = tid & 63;
  const int wave = tid >> 6;
  const int nl = lane & 15;
  const int kgrp = lane >> 4;
  const int jt0 = wave * 4;
  const int node0 = blockIdx.x * 32;

  // Persistent W fragments: 16 x f16x8 (64 VGPRs), L2-resident source.
  const f16x8* wp = reinterpret_cast<const f16x8*>(Wpk);
  f16x8 wfrag[4][4];
#pragma unroll
  for (int j4 = 0; j4 < 4; ++j4)
#pragma unroll
    for (int kt = 0; kt < 4; ++kt)
      wfrag[j4][kt] = wp[((jt0 + j4) * 4 + kt) * 64 + lane];

  // Bias (A-half only).
  f32x4 binit[4];
#pragma unroll
  for (int j4 = 0; j4 < 4; ++j4) {
    const int jt = jt0 + j4;
    if (jt < 8) {
      binit[j4] = *reinterpret_cast<const f32x4*>(b1 + jt * 16 + kgrp * 4);
    } else {
      binit[j4][0] = 0.f; binit[j4][1] = 0.f; binit[j4][2] = 0.f; binit[j4][3] = 0.f;
    }
  }

  // ---- Stage: thread t, round q handles fp16-linear 8B unit
  //      lin = q*2048 + t*8; row = lin>>8 (256B fp16 rows); col = lin&255.
  //      Global fp32 source byte = node(row)*512 + col*2 -> per instruction
  //      the wave reads 1KB CONTIGUOUS (dense lines). LDS dest XOR-swizzled.
  float4 sbuf[4];
#pragma unroll
  for (int q = 0; q < 4; ++q) {
    const int lin = q * 2048 + tid * 8;
    int node = node0 + (lin >> 8);
    if (node >= n_nodes) node = n_nodes - 1;  // clamp; stores guarded
    sbuf[q] = *reinterpret_cast<const float4*>(
        reinterpret_cast<const char*>(h) + (size_t)node * 512 + (lin & 255) * 2);
  }
#pragma unroll
  for (int q = 0; q < 4; ++q) {
    const int lin = q * 2048 + tid * 8;
    const int row = lin >> 8;
    const int col = lin & 255;
    const fp16v2 p0 = __builtin_amdgcn_cvt_pkrtz(sbuf[q].x, sbuf[q].y);
    const fp16v2 p1 = __builtin_amdgcn_cvt_pkrtz(sbuf[q].z, sbuf[q].w);
    f16x4 v;
    v[0] = (_Float16)p0[0]; v[1] = (_Float16)p0[1];
    v[2] = (_Float16)p1[0]; v[3] = (_Float16)p1[1];
    const int dst = row * 256 + (col ^ ((row & 7) << 4));
    *reinterpret_cast<f16x4*>(stage + dst) = v;
  }
  __syncthreads();

  // ---- Compute: per wave, 2 subtiles x 4 kt x 4 j4 MFMAs; fragments are
  //      single ds_read_b128 (swizzle-matched, ~2-way banks).
  f32x4 acc[2][4];
#pragma unroll
  for (int s = 0; s < 2; ++s)
#pragma unroll
    for (int j4 = 0; j4 < 4; ++j4) acc[s][j4] = binit[j4];

#pragma unroll
  for (int s = 0; s < 2; ++s) {
    const int row = s * 16 + nl;
#pragma unroll
    for (int kt = 0; kt < 4; ++kt) {
      const int addr = row * 256 + ((kt * 64 + kgrp * 16) ^ ((row & 7) << 4));
      const f16x8 hf = *reinterpret_cast<const f16x8*>(stage + addr);
#pragma unroll
      for (int j4 = 0; j4 < 4; ++j4)
        acc[s][j4] = __builtin_amdgcn_mfma_f32_16x16x32_f16(
            wfrag[j4][kt], hf, acc[s][j4], 0, 0, 0);
    }
  }

  // ---- Bounce accumulators into obuf (8B ds_writes, padded rows).
#pragma unroll
  for (int s = 0; s < 2; ++s) {
    const int row = s * 16 + nl;
#pragma unroll
    for (int j4 = 0; j4 < 4; ++j4) {
      const int jt = jt0 + j4;
      const int byte = row * 528 + ((jt & 7) * 16 + kgrp * 4) * 2 +
                       ((jt >= 8) ? 256 : 0);
      f16x4 v;
      v[0] = (_Float16)acc[s][j4][0];
      v[1] = (_Float16)acc[s][j4][1];
      v[2] = (_Float16)acc[s][j4][2];
      v[3] = (_Float16)acc[s][j4][3];
      *reinterpret_cast<f16x4*>(obuf + byte) = v;
    }
  }
  __syncthreads();

  // ---- Coalesced copyout: thread -> node tid>>4 (+16*half), 16B seg tid&15.
  const int cs = tid >> 4;
  const int seg = tid & 15;
#pragma unroll
  for (int half = 0; half < 2; ++half) {
    const int cn = half * 16 + cs;
    const int node = node0 + cn;
    if (node < n_nodes) {
      const f16x8 a = *reinterpret_cast<const f16x8*>(obuf + cn * 528 + seg * 16);
      const f16x8 b = *reinterpret_cast<const f16x8*>(obuf + cn * 528 + 256 + seg * 16);
      *reinterpret_cast<f16x8*>(Af + (size_t)node * HIDDEN + seg * 8) = a;
      *reinterpret_cast<f16x8*>(Bf + (size_t)node * HIDDEN + seg * 8) = b;
    }
  }
}

// ---------------------------------------------------------------------------
// Kernel 2 (v5, unchanged): per edge, score = relu(A[src]+B[dst]).W2 + b2.
// One wave per 16 edges; int4 index loads; packed fp16 add/relu + fdot2;
// merged butterfly reduction. ~47us = random-gather service ceiling (two
// structures identical; fp8 rows rejected on error budget).
// ---------------------------------------------------------------------------
__global__ __launch_bounds__(256) void edge_score_v5(
    const int* __restrict__ ei, const _Float16* __restrict__ Af,
    const _Float16* __restrict__ Bf, const float* __restrict__ W2,
    const float* __restrict__ b2, float* __restrict__ out, int n_edges) {
  const int wid = (int)((blockIdx.x * 256 + threadIdx.x) >> 6);
  const int lane = threadIdx.x & 63;
  const int e0 = wid * 16;
  if (e0 >= n_edges) return;

  int srcs[16], dsts[16];
  if (e0 + 16 <= n_edges) {
    const int4* sp = reinterpret_cast<const int4*>(ei + e0);
    const int4* dp = reinterpret_cast<const int4*>(ei + n_edges + e0);
#pragma unroll
    for (int q = 0; q < 4; ++q) {
      const int4 s4 = sp[q], d4 = dp[q];
      srcs[q * 4] = s4.x; srcs[q * 4 + 1] = s4.y; srcs[q * 4 + 2] = s4.z; srcs[q * 4 + 3] = s4.w;
      dsts[q * 4] = d4.x; dsts[q * 4 + 1] = d4.y; dsts[q * 4 + 2] = d4.z; dsts[q * 4 + 3] = d4.w;
    }
  } else {
#pragma unroll
    for (int k = 0; k < 16; ++k) {
      const int e = (e0 + k < n_edges) ? e0 + k : n_edges - 1;
      srcs[k] = ei[e];
      dsts[k] = ei[n_edges + e];
    }
  }

  const char* Afc = (const char*)Af;
  const char* Bfc = (const char*)Bf;
  const unsigned int loff = (unsigned int)(lane << 2);

  f16x2 av[16], bv[16];
#pragma unroll
  for (int k = 0; k < 16; ++k) {
    av[k] = *reinterpret_cast<const f16x2*>(Afc + (((unsigned int)srcs[k] << 8) + loff));
    bv[k] = *reinterpret_cast<const f16x2*>(Bfc + (((unsigned int)dsts[k] << 8) + loff));
  }

  const float2 w2v = reinterpret_cast<const float2*>(W2)[lane];
  const fp16v2 w2h = __builtin_amdgcn_cvt_pkrtz(w2v.x, w2v.y);
  const _Float16 h0 = (_Float16)0.f;

  float p[16];
#pragma unroll
  for (int k = 0; k < 16; ++k) {
    f16x2 s = av[k] + bv[k];                 // v_pk_add_f16
    s[0] = s[0] > h0 ? s[0] : h0;            // pk max vs 0
    s[1] = s[1] > h0 ? s[1] : h0;
    p[k] = __builtin_amdgcn_fdot2(__builtin_bit_cast(fp16v2, s), w2h, 0.f, false);
  }

  auto mrg = [&](float a, float b, int off) {
    const float as = a + __shfl_xor(a, off, 64);
    const float bs = b + __shfl_xor(b, off, 64);
    return (lane & off) ? bs : as;
  };
  float q[8];
#pragma unroll
  for (int i = 0; i < 8; ++i) q[i] = mrg(p[2 * i], p[2 * i + 1], 1);
  float r[4];
#pragma unroll
  for (int i = 0; i < 4; ++i) r[i] = mrg(q[2 * i], q[2 * i + 1], 2);
  float s2[2];
#pragma unroll
  for (int i = 0; i < 2; ++i) s2[i] = mrg(r[2 * i], r[2 * i + 1], 4);
  float t = mrg(s2[0], s2[1], 8);
  t += __shfl_xor(t, 16, 64);
  t += __shfl_xor(t, 32, 64);

  if (lane < 16 && e0 + lane < n_edges) out[e0 + lane] = t + b2[0];
}

// ---------------------------------------------------------------------------
// Fallback (ws too small): fused fp32 per-edge compute.
// ---------------------------------------------------------------------------
__global__ __launch_bounds__(256) void fused_fallback(
    const float* __restrict__ h, const int* __restrict__ ei,
    const float* __restrict__ W1, const float* __restrict__ b1,
    const float* __restrict__ W2, const float* __restrict__ b2,
    float* __restrict__ out, int n_edges) {
  const int e = (int)((blockIdx.x * 256 + threadIdx.x) >> 6);
  const int lane = threadIdx.x & 63;
  if (e >= n_edges) return;
  const int src = ei[e], dst = ei[n_edges + e];
  const float* hs = h + (size_t)src * HIDDEN;
  const float* hd = h + (size_t)dst * HIDDEN;
  float acc0 = b1[lane], acc1 = b1[lane + 64];
  for (int k = 0; k < HIDDEN; ++k) {
    const float s = hs[k], d = hd[k];
    acc0 = fmaf(s, W1[k * HIDDEN + lane], acc0);
    acc0 = fmaf(d, W1[(k + HIDDEN) * HIDDEN + lane], acc0);
    acc1 = fmaf(s, W1[k * HIDDEN + lane + 64], acc1);
    acc1 = fmaf(d, W1[(k + HIDDEN) * HIDDEN + lane + 64], acc1);
  }
  acc0 = acc0 > 0.f ? acc0 : 0.f;
  acc1 = acc1 > 0.f ? acc1 : 0.f;
  float p = fmaf(acc0, W2[lane], acc1 * W2[lane + 64]);
#pragma unroll
  for (int off = 32; off >= 1; off >>= 1) p += __shfl_down(p, off, 64);
  if (lane == 0) out[e] = p + b2[0];
}

extern "C" void kernel_launch(void* const* d_in, const int* in_sizes, int n_in,
                              void* d_out, int out_size, void* d_ws, size_t ws_size,
                              hipStream_t stream) {
  const float* h  = (const float*)d_in[0];
  const int*   ei = (const int*)d_in[1];
  const float* W1 = (const float*)d_in[2];
  const float* b1 = (const float*)d_in[3];
  const float* W2 = (const float*)d_in[4];
  const float* b2 = (const float*)d_in[5];
  float* out = (float*)d_out;

  const int n_nodes = in_sizes[0] / HIDDEN;  // 100000
  const int n_edges = in_sizes[1] / 2;       // 640000

  const size_t wpk_halfs  = 64 * 64 * 8;                       // 32768
  const size_t proj_halfs = (size_t)n_nodes * HIDDEN;          // 12.8M
  const size_t need = (wpk_halfs + 2 * proj_halfs) * sizeof(_Float16);

  if (ws_size >= need) {
    _Float16* Wpk = (_Float16*)d_ws;
    _Float16* A   = Wpk + wpk_halfs;
    _Float16* B   = A + proj_halfs;

    prep_w<<<64, 64, 0, stream>>>(W1, Wpk);

    const int gblocks = (n_nodes + 31) / 32;      // 3125
    gemm_mfma_v10<<<gblocks, 256, 0, stream>>>(h, Wpk, b1, A, B, n_nodes);

    const int nwaves = (n_edges + 15) / 16;
    const int eblocks = (nwaves + 3) / 4;
    edge_score_v5<<<eblocks, 256, 0, stream>>>(ei, A, B, W2, b2, out, n_edges);
  } else {
    const int eblocks = (n_edges + 3) / 4;
    fused_fallback<<<eblocks, 256, 0, stream>>>(h, ei, W1, b1, W2, b2, out, n_edges);
  }
}

// Round 14
// 74.600 us; speedup vs baseline: 1.1952x; 1.0395x over previous
//
#include <hip/hip_runtime.h>

#define HIDDEN 128

typedef _Float16 f16x8 __attribute__((ext_vector_type(8)));
typedef _Float16 f16x4 __attribute__((ext_vector_type(4)));
typedef _Float16 f16x2 __attribute__((ext_vector_type(2)));
typedef __fp16   fp16v2 __attribute__((ext_vector_type(2)));  // builtin ABI type
typedef float f32x4 __attribute__((ext_vector_type(4)));

// ---------------------------------------------------------------------------
// Kernel 0: pack W1 (fp32, (256,128)) into fp16 MFMA fragments.
// Bmat (K=128, N=256): Bmat[k][n] = n<128 ? W1[k][n] : W1[128+k][n-128]
// Wpk[((jt*4+kt)*64 + lane)*8 + j] = Bmat[kt*32+(lane>>4)*8+j][jt*16+(lane&15)]
// Serves as A-operand fragment (A = Bmat^T): lane holds A[lane&15][(lane>>4)*8+j].
// ---------------------------------------------------------------------------
__global__ __launch_bounds__(64) void prep_w(const float* __restrict__ W1,
                                             _Float16* __restrict__ Wpk) {
  const int blk = blockIdx.x;        // 0..63 = jt*4 + kt
  const int jt = blk >> 2;
  const int kt = blk & 3;
  const int lane = threadIdx.x;      // 0..63
  const int col = jt * 16 + (lane & 15);         // feature 0..255
  const int kbase = kt * 32 + (lane >> 4) * 8;   // 0..120
  f16x8 v;
#pragma unroll
  for (int j = 0; j < 8; ++j) {
    const int k = kbase + j;
    const float w = (col < HIDDEN) ? W1[k * HIDDEN + col]
                                   : W1[(HIDDEN + k) * HIDDEN + (col - HIDDEN)];
    v[j] = (_Float16)w;
  }
  *reinterpret_cast<f16x8*>(Wpk + ((size_t)blk * 64 + lane) * 8) = v;
}

// ---------------------------------------------------------------------------
// Kernel 1 (v11): v10 x 2-tile unroll. 64 nodes/block (two 32-node tiles),
// wfrag/binit loaded ONCE per block; both tiles' staging loads issued up
// front so tile-1 latency hides under tile-0 compute+copyout. Barrier order:
// stage reads happen before B2 (so SW1 after B2 is safe); obuf reads of
// copyout-0 are data-dependency-complete before B3 (so compute-1's obuf
// writes after B3 are safe). No min-waves launch_bounds (spill lesson).
// ---------------------------------------------------------------------------
__global__ __launch_bounds__(256) void gemm_mfma_v11(
    const float* __restrict__ h, const _Float16* __restrict__ Wpk,
    const float* __restrict__ b1, _Float16* __restrict__ Af,
    _Float16* __restrict__ Bf, int n_nodes) {
  __shared__ __align__(16) char stage[32 * 256];   // fp16 h-tile, swizzled
  __shared__ __align__(16) char obuf[32 * 528];    // output bounce

  const int tid = threadIdx.x;
  const int lane = tid & 63;
  const int wave = tid >> 6;
  const int nl = lane & 15;
  const int kgrp = lane >> 4;
  const int jt0 = wave * 4;
  const int node0 = blockIdx.x * 64;

  // Persistent W fragments + bias (once per 64 nodes).
  const f16x8* wp = reinterpret_cast<const f16x8*>(Wpk);
  f16x8 wfrag[4][4];
#pragma unroll
  for (int j4 = 0; j4 < 4; ++j4)
#pragma unroll
    for (int kt = 0; kt < 4; ++kt)
      wfrag[j4][kt] = wp[((jt0 + j4) * 4 + kt) * 64 + lane];

  f32x4 binit[4];
#pragma unroll
  for (int j4 = 0; j4 < 4; ++j4) {
    const int jt = jt0 + j4;
    if (jt < 8) {
      binit[j4] = *reinterpret_cast<const f32x4*>(b1 + jt * 16 + kgrp * 4);
    } else {
      binit[j4][0] = 0.f; binit[j4][1] = 0.f; binit[j4][2] = 0.f; binit[j4][3] = 0.f;
    }
  }

  auto STAGELOAD = [&](float4* sbuf, int base) {
#pragma unroll
    for (int q = 0; q < 4; ++q) {
      const int lin = q * 2048 + tid * 8;
      int node = base + (lin >> 8);
      if (node >= n_nodes) node = n_nodes - 1;  // clamp; stores guarded
      sbuf[q] = *reinterpret_cast<const float4*>(
          reinterpret_cast<const char*>(h) + (size_t)node * 512 + (lin & 255) * 2);
    }
  };

  auto CVT_SW = [&](const float4* sbuf) {
#pragma unroll
    for (int q = 0; q < 4; ++q) {
      const int lin = q * 2048 + tid * 8;
      const int row = lin >> 8;
      const int col = lin & 255;
      const fp16v2 p0 = __builtin_amdgcn_cvt_pkrtz(sbuf[q].x, sbuf[q].y);
      const fp16v2 p1 = __builtin_amdgcn_cvt_pkrtz(sbuf[q].z, sbuf[q].w);
      f16x4 v;
      v[0] = (_Float16)p0[0]; v[1] = (_Float16)p0[1];
      v[2] = (_Float16)p1[0]; v[3] = (_Float16)p1[1];
      const int dst = row * 256 + (col ^ ((row & 7) << 4));
      *reinterpret_cast<f16x4*>(stage + dst) = v;
    }
  };

  auto COMPUTE_OBUF = [&]() {
    f32x4 acc[2][4];
#pragma unroll
    for (int s = 0; s < 2; ++s)
#pragma unroll
      for (int j4 = 0; j4 < 4; ++j4) acc[s][j4] = binit[j4];
#pragma unroll
    for (int s = 0; s < 2; ++s) {
      const int row = s * 16 + nl;
#pragma unroll
      for (int kt = 0; kt < 4; ++kt) {
        const int addr = row * 256 + ((kt * 64 + kgrp * 16) ^ ((row & 7) << 4));
        const f16x8 hf = *reinterpret_cast<const f16x8*>(stage + addr);
#pragma unroll
        for (int j4 = 0; j4 < 4; ++j4)
          acc[s][j4] = __builtin_amdgcn_mfma_f32_16x16x32_f16(
              wfrag[j4][kt], hf, acc[s][j4], 0, 0, 0);
      }
    }
#pragma unroll
    for (int s = 0; s < 2; ++s) {
      const int row = s * 16 + nl;
#pragma unroll
      for (int j4 = 0; j4 < 4; ++j4) {
        const int jt = jt0 + j4;
        const int byte = row * 528 + ((jt & 7) * 16 + kgrp * 4) * 2 +
                         ((jt >= 8) ? 256 : 0);
        f16x4 v;
        v[0] = (_Float16)acc[s][j4][0];
        v[1] = (_Float16)acc[s][j4][1];
        v[2] = (_Float16)acc[s][j4][2];
        v[3] = (_Float16)acc[s][j4][3];
        *reinterpret_cast<f16x4*>(obuf + byte) = v;
      }
    }
  };

  const int cs = tid >> 4;
  const int seg = tid & 15;
  auto COPYOUT = [&](int base) {
#pragma unroll
    for (int half = 0; half < 2; ++half) {
      const int cn = half * 16 + cs;
      const int node = base + cn;
      if (node < n_nodes) {
        const f16x8 a = *reinterpret_cast<const f16x8*>(obuf + cn * 528 + seg * 16);
        const f16x8 b = *reinterpret_cast<const f16x8*>(obuf + cn * 528 + 256 + seg * 16);
        *reinterpret_cast<f16x8*>(Af + (size_t)node * HIDDEN + seg * 8) = a;
        *reinterpret_cast<f16x8*>(Bf + (size_t)node * HIDDEN + seg * 8) = b;
      }
    }
  };

  float4 sbuf0[4], sbuf1[4];
  STAGELOAD(sbuf0, node0);        // tile-0 loads in flight
  STAGELOAD(sbuf1, node0 + 32);   // tile-1 loads in flight (hidden latency)

  // ---- tile 0 ----
  CVT_SW(sbuf0);
  __syncthreads();                // B1: stage complete
  COMPUTE_OBUF();
  __syncthreads();                // B2: obuf complete; stage reads done
  COPYOUT(node0);

  // ---- tile 1 ----
  CVT_SW(sbuf1);                  // safe: after B2 (stage reads done)
  __syncthreads();                // B3: stage complete; copyout-0 LDS reads done
  COMPUTE_OBUF();                 // safe: obuf rewrite after B3
  __syncthreads();                // B4: obuf complete
  COPYOUT(node0 + 32);
}

// ---------------------------------------------------------------------------
// Kernel 2 (v5, reverted verbatim — v6's wave-quarter wide-load variant
// diverged under graph replay with no statically-identifiable bug; v5 passed
// twice at ~46us). Per edge: score = relu(A[src]+B[dst]).W2 + b2. One wave
// per 16 edges; int4 index loads; packed fp16 add/relu + fdot2; merged
// butterfly reduction.
// ---------------------------------------------------------------------------
__global__ __launch_bounds__(256) void edge_score_v5(
    const int* __restrict__ ei, const _Float16* __restrict__ Af,
    const _Float16* __restrict__ Bf, const float* __restrict__ W2,
    const float* __restrict__ b2, float* __restrict__ out, int n_edges) {
  const int wid = (int)((blockIdx.x * 256 + threadIdx.x) >> 6);
  const int lane = threadIdx.x & 63;
  const int e0 = wid * 16;
  if (e0 >= n_edges) return;

  int srcs[16], dsts[16];
  if (e0 + 16 <= n_edges) {
    const int4* sp = reinterpret_cast<const int4*>(ei + e0);
    const int4* dp = reinterpret_cast<const int4*>(ei + n_edges + e0);
#pragma unroll
    for (int q = 0; q < 4; ++q) {
      const int4 s4 = sp[q], d4 = dp[q];
      srcs[q * 4] = s4.x; srcs[q * 4 + 1] = s4.y; srcs[q * 4 + 2] = s4.z; srcs[q * 4 + 3] = s4.w;
      dsts[q * 4] = d4.x; dsts[q * 4 + 1] = d4.y; dsts[q * 4 + 2] = d4.z; dsts[q * 4 + 3] = d4.w;
    }
  } else {
#pragma unroll
    for (int k = 0; k < 16; ++k) {
      const int e = (e0 + k < n_edges) ? e0 + k : n_edges - 1;
      srcs[k] = ei[e];
      dsts[k] = ei[n_edges + e];
    }
  }

  const char* Afc = (const char*)Af;
  const char* Bfc = (const char*)Bf;
  const unsigned int loff = (unsigned int)(lane << 2);

  f16x2 av[16], bv[16];
#pragma unroll
  for (int k = 0; k < 16; ++k) {
    av[k] = *reinterpret_cast<const f16x2*>(Afc + (((unsigned int)srcs[k] << 8) + loff));
    bv[k] = *reinterpret_cast<const f16x2*>(Bfc + (((unsigned int)dsts[k] << 8) + loff));
  }

  const float2 w2v = reinterpret_cast<const float2*>(W2)[lane];
  const fp16v2 w2h = __builtin_amdgcn_cvt_pkrtz(w2v.x, w2v.y);
  const _Float16 h0 = (_Float16)0.f;

  float p[16];
#pragma unroll
  for (int k = 0; k < 16; ++k) {
    f16x2 s = av[k] + bv[k];                 // v_pk_add_f16
    s[0] = s[0] > h0 ? s[0] : h0;            // pk max vs 0
    s[1] = s[1] > h0 ? s[1] : h0;
    p[k] = __builtin_amdgcn_fdot2(__builtin_bit_cast(fp16v2, s), w2h, 0.f, false);
  }

  auto mrg = [&](float a, float b, int off) {
    const float as = a + __shfl_xor(a, off, 64);
    const float bs = b + __shfl_xor(b, off, 64);
    return (lane & off) ? bs : as;
  };
  float q[8];
#pragma unroll
  for (int i = 0; i < 8; ++i) q[i] = mrg(p[2 * i], p[2 * i + 1], 1);
  float r[4];
#pragma unroll
  for (int i = 0; i < 4; ++i) r[i] = mrg(q[2 * i], q[2 * i + 1], 2);
  float s2[2];
#pragma unroll
  for (int i = 0; i < 2; ++i) s2[i] = mrg(r[2 * i], r[2 * i + 1], 4);
  float t = mrg(s2[0], s2[1], 8);
  t += __shfl_xor(t, 16, 64);
  t += __shfl_xor(t, 32, 64);

  if (lane < 16 && e0 + lane < n_edges) out[e0 + lane] = t + b2[0];
}

// ---------------------------------------------------------------------------
// Fallback (ws too small): fused fp32 per-edge compute.
// ---------------------------------------------------------------------------
__global__ __launch_bounds__(256) void fused_fallback(
    const float* __restrict__ h, const int* __restrict__ ei,
    const float* __restrict__ W1, const float* __restrict__ b1,
    const float* __restrict__ W2, const float* __restrict__ b2,
    float* __restrict__ out, int n_edges) {
  const int e = (int)((blockIdx.x * 256 + threadIdx.x) >> 6);
  const int lane = threadIdx.x & 63;
  if (e >= n_edges) return;
  const int src = ei[e], dst = ei[n_edges + e];
  const float* hs = h + (size_t)src * HIDDEN;
  const float* hd = h + (size_t)dst * HIDDEN;
  float acc0 = b1[lane], acc1 = b1[lane + 64];
  for (int k = 0; k < HIDDEN; ++k) {
    const float s = hs[k], d = hd[k];
    acc0 = fmaf(s, W1[k * HIDDEN + lane], acc0);
    acc0 = fmaf(d, W1[(k + HIDDEN) * HIDDEN + lane], acc0);
    acc1 = fmaf(s, W1[k * HIDDEN + lane + 64], acc1);
    acc1 = fmaf(d, W1[(k + HIDDEN) * HIDDEN + lane + 64], acc1);
  }
  acc0 = acc0 > 0.f ? acc0 : 0.f;
  acc1 = acc1 > 0.f ? acc1 : 0.f;
  float p = fmaf(acc0, W2[lane], acc1 * W2[lane + 64]);
#pragma unroll
  for (int off = 32; off >= 1; off >>= 1) p += __shfl_down(p, off, 64);
  if (lane == 0) out[e] = p + b2[0];
}

extern "C" void kernel_launch(void* const* d_in, const int* in_sizes, int n_in,
                              void* d_out, int out_size, void* d_ws, size_t ws_size,
                              hipStream_t stream) {
  const float* h  = (const float*)d_in[0];
  const int*   ei = (const int*)d_in[1];
  const float* W1 = (const float*)d_in[2];
  const float* b1 = (const float*)d_in[3];
  const float* W2 = (const float*)d_in[4];
  const float* b2 = (const float*)d_in[5];
  float* out = (float*)d_out;

  const int n_nodes = in_sizes[0] / HIDDEN;  // 100000
  const int n_edges = in_sizes[1] / 2;       // 640000

  const size_t wpk_halfs  = 64 * 64 * 8;                       // 32768
  const size_t proj_halfs = (size_t)n_nodes * HIDDEN;          // 12.8M
  const size_t need = (wpk_halfs + 2 * proj_halfs) * sizeof(_Float16);

  if (ws_size >= need) {
    _Float16* Wpk = (_Float16*)d_ws;
    _Float16* A   = Wpk + wpk_halfs;
    _Float16* B   = A + proj_halfs;

    prep_w<<<64, 64, 0, stream>>>(W1, Wpk);

    const int gblocks = (n_nodes + 63) / 64;      // 1563
    gemm_mfma_v11<<<gblocks, 256, 0, stream>>>(h, Wpk, b1, A, B, n_nodes);

    const int nwaves = (n_edges + 15) / 16;
    const int eblocks = (nwaves + 3) / 4;
    edge_score_v5<<<eblocks, 256, 0, stream>>>(ei, A, B, W2, b2, out, n_edges);
  } else {
    const int eblocks = (n_edges + 3) / 4;
    fused_fallback<<<eblocks, 256, 0, stream>>>(h, ei, W1, b1, W2, b2, out, n_edges);
  }
}